// Round 8
// baseline (143.885 us; speedup 1.0000x reference)
//
#include <hip/hip_runtime.h>
#include <cstdint>
#include <cstddef>

// LogMM_19490561589867: x [8,2048,1024] f32, matrix [1024,1024] f32
// out = log(max(x @ matrix, tiny))  [8,2048,1024] f32
// Round-15: revert gemm to the EXACT proven round-0 config (132.4us, best).
// Change: prep A-conversion block mapping is now XCD-ALIGNED. Old: block i
// -> rows i*4 (round-robin -> Ab panel P written through all 8 XCD L2s,
// while gemm's reader of P is on XCD P>>3: 7/8 cross-XCD re-reads).
// New: block i (XCD=i&7) converts rows [(i&7)*2048 + (i>>3)*4, +4), so Ab
// writes land in the SAME XCD L2 that the gemm re-reads (2 MiB/XCD < 4 MiB).
// Plus nontemporal hints on prep's one-shot f32 streaming reads (A, B) so
// they don't evict the freshly-written Ab from L2.
// Numerics identical: fp8 e4m3 RNE quantized GEMM, absmax 0.03125 (floor).
#define M_GLOB 16384
#define N_GLOB 1024
#define K_GLOB 1024

#define BM 256    // block tile rows (2 wave-rows x 128)
#define BN 128    // block tile cols (2 wave-cols x 64)
#define BKF 128   // fp8 K-tile bytes: 8 k-iters; 2 MX K=64 steps per iter

typedef unsigned char  u8;
typedef unsigned short u16;
typedef __attribute__((ext_vector_type(4))) float  f32x4;
typedef __attribute__((ext_vector_type(16))) float f32x16;
typedef __attribute__((ext_vector_type(4))) unsigned int  u32x4;
typedef __attribute__((ext_vector_type(2))) unsigned int  u32x2;
typedef __attribute__((ext_vector_type(8))) int  i32x8;
typedef __attribute__((ext_vector_type(8))) __bf16 bf16x8;

// truncating pack (fallback fused path — round-1 proven numerics)
static __device__ __forceinline__ unsigned pack2_bf16(float lo, float hi) {
    unsigned bl = __builtin_bit_cast(unsigned, lo);
    unsigned bh = __builtin_bit_cast(unsigned, hi);
    return (bh & 0xFFFF0000u) | (bl >> 16);
}

// 4 fp32 -> 4 fp8 e4m3 bytes (HW RNE, OCP on gfx950)
static __device__ __forceinline__ unsigned cvt4_fp8(float a, float b, float c, float d) {
    int w = __builtin_amdgcn_cvt_pk_fp8_f32(a, b, 0, false);
    w = __builtin_amdgcn_cvt_pk_fp8_f32(c, d, w, true);
    return (unsigned)w;
}

// Raw workgroup barrier: compiler memory-clobber but NO vmcnt drain —
// pending global->VGPR prefetch loads stay in flight across it (m139).
static __device__ __forceinline__ void barrier_raw() {
    asm volatile("s_barrier" ::: "memory");
}

// ---------------------------------------------------------------------------
// Prep (merged): blocks [0, nA): Ab_fp8 = e4m3(A), 16 floats/thread,
//   XCD-aligned: block i converts rows [(i&7)*2048 + (i>>3)*4, +4) so the
//   Ab panel lands in the L2 of the XCD whose gemm blocks re-read it.
// blocks [nA, nA+1024): Bt_fp8[n][k] = e4m3(B[k][n]), 32x32 tiles.
// One-shot f32 reads are nontemporal (don't evict Ab from L2).
// ---------------------------------------------------------------------------
__global__ __launch_bounds__(256)
void prep_fp8_kernel(const float* __restrict__ A, u8* __restrict__ Ab,
                     const float* __restrict__ B, u8* __restrict__ Bt, int nA) {
    __shared__ float tile[32][33];
    const int tid = threadIdx.x;
    if ((int)blockIdx.x < nA) {
        const int blk = (int)blockIdx.x;
        const int xcd = blk & 7;
        const int sub = blk >> 3;             // 0..511
        // rows [xcd*2048 + sub*4, +4) -> 4096 f32; thread covers 16.
        const size_t i = ((size_t)xcd * 2048 + (size_t)sub * 4) * K_GLOB
                       + (size_t)tid * 16;
        f32x4 f0 = __builtin_nontemporal_load((const f32x4*)(A + i));
        f32x4 f1 = __builtin_nontemporal_load((const f32x4*)(A + i + 4));
        f32x4 f2 = __builtin_nontemporal_load((const f32x4*)(A + i + 8));
        f32x4 f3 = __builtin_nontemporal_load((const f32x4*)(A + i + 12));
        u32x4 o;
        o.x = cvt4_fp8(f0.x, f0.y, f0.z, f0.w);
        o.y = cvt4_fp8(f1.x, f1.y, f1.z, f1.w);
        o.z = cvt4_fp8(f2.x, f2.y, f2.z, f2.w);
        o.w = cvt4_fp8(f3.x, f3.y, f3.z, f3.w);
        *(u32x4*)(Ab + i) = o;                // normal store: stays in L2
    } else {
        const int bid = (int)blockIdx.x - nA;
        const int n0 = (bid & 31) * 32;
        const int k0 = (bid >> 5) * 32;
        const int tx = tid & 31;
        const int ty = tid >> 5;   // 0..7
#pragma unroll
        for (int i = 0; i < 32; i += 8)
            tile[ty + i][tx] = __builtin_nontemporal_load(
                &B[(size_t)(k0 + ty + i) * N_GLOB + n0 + tx]);
        __syncthreads();
#pragma unroll
        for (int i = 0; i < 32; i += 8) {
            int w = __builtin_amdgcn_cvt_pk_fp8_f32(tile[tx][ty + i], 0.f, 0, false);
            Bt[(size_t)(n0 + ty + i) * K_GLOB + k0 + tx] = (u8)(w & 0xFF);
        }
    }
}

// ---------------------------------------------------------------------------
// Main GEMM — EXACT round-0 proven kernel (132.4us config, best measured).
// MX-scaled fp8 (unit scales): Ab [M][K] fp8, Bt [N][K] fp8, f32 C.
//  - mfma_scale_f32_32x32x64_f8f6f4, scales 0x7F (=1.0): pure fp8 at 2x rate.
//  - Block 256x128; wave tile 128x64 = 4x2 of 32x32 (acc 128 VGPR).
//  - Software pipeline: tile kt+1 prefetched into VGPRs right after the
//    staging barrier; ds_write at the next iteration top consumes them.
//    End-of-compute barrier is raw s_barrier (no vmcnt drain).
//  - XOR swizzle (measured zero-conflict): LDS 16B-chunk position p holds
//    global chunk c = p ^ (row&7).
//  - Epilogue: 4 quarters of 64 rows staged through LDS (stride 132) ->
//    coalesced float4 nontemporal stores (proven WRITE_SIZE == ideal).
// ---------------------------------------------------------------------------
__global__ __launch_bounds__(256, 2)
void gemm_mx_kernel(const u8* __restrict__ A,
                    const u8* __restrict__ Bt,
                    float* __restrict__ C)
{
    // As: 256x128 fp8 = 32 KB @0 ; Bs: 128x128 fp8 = 16 KB @32768.
    // Epilogue reuses first 33792 B as Cs (64 rows x 132 f32).
    __shared__ __attribute__((aligned(16))) char smem[49152];
    float* Cs = (float*)smem;

    const int tid  = threadIdx.x;
    const int wave = tid >> 6;
    const int lane = tid & 63;
    const int wr   = wave >> 1;     // wave row: 128 rows each
    const int wc   = wave & 1;      // wave col: 64 cols each
    const int l32  = lane & 31;
    const int half = lane >> 5;     // k-half selector of the MFMA operand

    // XCD-contiguous swizzle: 8 blocks sharing an A panel land on one XCD.
    const int b    = blockIdx.x;          // 0..511
    const int xcd  = b & 7;
    const int idx  = b >> 3;              // 0..63
    const int m0   = (xcd * 8 + (idx >> 3)) * BM;
    const int n0   = (idx & 7) * BN;

    // Staging map: slot s covers 8 rows. Lane L -> row (L>>3), LDS chunk
    // position p = L&7 holding global chunk c = p ^ (L>>3).
    const int srow = lane >> 3;                  // 0..7
    const int sp   = lane & 7;                   // LDS chunk position
    const int sc   = sp ^ srow;                  // swizzled global 16B chunk
    const u8* gA = A  + (size_t)(m0 + srow) * K_GLOB + sc * 16;
    const u8* gB = Bt + (size_t)(n0 + srow) * K_GLOB + sc * 16;

    f32x16 acc[4][2];
#pragma unroll
    for (int i = 0; i < 4; ++i)
#pragma unroll
        for (int j = 0; j < 2; ++j)
#pragma unroll
            for (int r = 0; r < 16; ++r)
                acc[i][j][r] = 0.f;

    const int swz = lane & 7;        // fragment row & 7 (row = base32 + l32)
    const int scale1 = 0x7F7F7F7F;   // e8m0 127 = 2^0 in every byte

    // ---- prologue: load tile kt=0 into registers
    u32x4 ra[8], rb[4];
#pragma unroll
    for (int s = 0; s < 8; ++s)
        ra[s] = *(const u32x4*)(gA + (size_t)((s * 4 + wave) * 8) * K_GLOB);
#pragma unroll
    for (int s = 0; s < 4; ++s)
        rb[s] = *(const u32x4*)(gB + (size_t)((s * 4 + wave) * 8) * K_GLOB);

    for (int kt = 0; kt < K_GLOB / BKF; ++kt) {
        // ---- stage current tile regs -> LDS (waits vmcnt for these loads)
#pragma unroll
        for (int s = 0; s < 8; ++s) {
            const int row = (s * 4 + wave) * 8 + srow;
            *(u32x4*)(smem + row * 128 + sp * 16) = ra[s];
        }
#pragma unroll
        for (int s = 0; s < 4; ++s) {
            const int row = (s * 4 + wave) * 8 + srow;
            *(u32x4*)(smem + 32768 + row * 128 + sp * 16) = rb[s];
        }
        __syncthreads();   // vmcnt already 0 here; drains lgkm (LDS visibility)

        // ---- prefetch tile kt+1 into regs (overlaps the compute below)
        if (kt + 1 < K_GLOB / BKF) {
            const size_t k1 = (size_t)(kt + 1) * BKF;
#pragma unroll
            for (int s = 0; s < 8; ++s)
                ra[s] = *(const u32x4*)(gA + (size_t)((s * 4 + wave) * 8) * K_GLOB + k1);
#pragma unroll
            for (int s = 0; s < 4; ++s)
                rb[s] = *(const u32x4*)(gB + (size_t)((s * 4 + wave) * 8) * K_GLOB + k1);
        }

        // ---- compute on LDS tile
#pragma unroll
        for (int s = 0; s < 2; ++s) {           // two K=64 steps per kt
            const int c0 = s * 4 + half * 2;
            const int p0 = ((c0    ) ^ swz) * 16;
            const int p1 = ((c0 + 1) ^ swz) * 16;
            i32x8 af[4], bf[2];
#pragma unroll
            for (int i = 0; i < 4; ++i) {
                const int row = wr * 128 + i * 32 + l32;
                u32x4 lo = *(const u32x4*)(smem + row * 128 + p0);
                u32x4 hi = *(const u32x4*)(smem + row * 128 + p1);
                af[i][0] = lo.x; af[i][1] = lo.y; af[i][2] = lo.z; af[i][3] = lo.w;
                af[i][4] = hi.x; af[i][5] = hi.y; af[i][6] = hi.z; af[i][7] = hi.w;
            }
#pragma unroll
            for (int j = 0; j < 2; ++j) {
                const int row = wc * 64 + j * 32 + l32;
                u32x4 lo = *(const u32x4*)(smem + 32768 + row * 128 + p0);
                u32x4 hi = *(const u32x4*)(smem + 32768 + row * 128 + p1);
                bf[j][0] = lo.x; bf[j][1] = lo.y; bf[j][2] = lo.z; bf[j][3] = lo.w;
                bf[j][4] = hi.x; bf[j][5] = hi.y; bf[j][6] = hi.z; bf[j][7] = hi.w;
            }
#pragma unroll
            for (int i = 0; i < 4; ++i)
#pragma unroll
                for (int j = 0; j < 2; ++j)
                    acc[i][j] = __builtin_amdgcn_mfma_scale_f32_32x32x64_f8f6f4(
                        af[i], bf[j], acc[i][j],
                        0 /*cbsz: A=fp8 e4m3*/, 0 /*blgp: B=fp8 e4m3*/,
                        0, scale1, 0, scale1);
        }
        // End-of-read fence: raw barrier, does NOT drain the kt+1 prefetch.
        barrier_raw();
    }

    // ---- epilogue: log(max(y,tiny)) staged through LDS in 64-row quarters.
    // 32x32 C/D layout (HW-verified): col=lane&31, row32=(r&3)+8*(r>>2)+4*half.
    const float LN2 = 0.69314718055994530942f;
    const int c4 = tid & 31;
    const int r0 = tid >> 5;
#pragma unroll
    for (int h = 0; h < 4; ++h) {
        __syncthreads();
        if (wr == (h >> 1)) {
#pragma unroll
            for (int ii = 0; ii < 2; ++ii) {
                const int i = (h & 1) * 2 + ii;
#pragma unroll
                for (int j = 0; j < 2; ++j) {
                    const int col = wc * 64 + j * 32 + l32;
#pragma unroll
                    for (int r = 0; r < 16; ++r) {
                        const int row32 = (r & 3) + 8 * (r >> 2) + 4 * half;
                        float v = fmaxf(acc[i][j][r], 1.17549435e-38f);
                        Cs[(ii * 32 + row32) * 132 + col] = __log2f(v) * LN2;
                    }
                }
            }
        }
        __syncthreads();
#pragma unroll
        for (int s2 = 0; s2 < 8; ++s2) {
            const int row = s2 * 8 + r0;
            f32x4 v = *(const f32x4*)&Cs[row * 132 + c4 * 4];
            __builtin_nontemporal_store(v,
                (f32x4*)&C[(size_t)(m0 + h * 64 + row) * N_GLOB + n0 + c4 * 4]);
        }
    }
}

// ---------------------------------------------------------------------------
// Fallback (round-1 kernel): fused fp32->bf16 staging, padded LDS.
// Used only if ws can't hold the fp8 buffers (17 MiB).
// ---------------------------------------------------------------------------
#define FBM 128
#define FBN 128
#define LDK 40
__global__ __launch_bounds__(256)
void logmm_fused_kernel(const float* __restrict__ A,
                        const float* __restrict__ Bf,
                        float* __restrict__ C)
{
    __shared__ u16 As[FBM][LDK];
    __shared__ u16 Bs[FBN][LDK];

    const int tid  = threadIdx.x;
    const int lane = tid & 63;
    const int wave = tid >> 6;
    const int wr   = wave >> 1;
    const int wc   = wave & 1;
    const int quad = lane >> 4;
    const int l16  = lane & 15;

    const int m0 = blockIdx.y * FBM;
    const int n0 = blockIdx.x * FBN;

    f32x4 acc[4][4];
#pragma unroll
    for (int i = 0; i < 4; ++i)
#pragma unroll
        for (int j = 0; j < 4; ++j)
            acc[i][j] = f32x4{0.f, 0.f, 0.f, 0.f};

    const int ga_row = tid >> 2;
    const int ga_c8  = (tid & 3) * 8;
    const int fb_nt = tid >> 3;
    const int fb_kt = tid & 7;

    for (int kt = 0; kt < K_GLOB / 32; ++kt) {
        const int k0 = kt * 32;
#pragma unroll
        for (int s = 0; s < 2; ++s) {
            const int row = ga_row + s * 64;
            const float* src = A + (size_t)(m0 + row) * K_GLOB + k0 + ga_c8;
            f32x4 f0 = *(const f32x4*)src;
            f32x4 f1 = *(const f32x4*)(src + 4);
            u32x4 o;
            o.x = pack2_bf16(f0.x, f0.y);
            o.y = pack2_bf16(f0.z, f0.w);
            o.z = pack2_bf16(f1.x, f1.y);
            o.w = pack2_bf16(f1.z, f1.w);
            *(u32x4*)&As[row][ga_c8] = o;
        }
        {
            f32x4 r0 = *(const f32x4*)(Bf + (size_t)(k0 + fb_kt * 4 + 0) * N_GLOB + n0 + fb_nt * 4);
            f32x4 r1 = *(const f32x4*)(Bf + (size_t)(k0 + fb_kt * 4 + 1) * N_GLOB + n0 + fb_nt * 4);
            f32x4 r2 = *(const f32x4*)(Bf + (size_t)(k0 + fb_kt * 4 + 2) * N_GLOB + n0 + fb_nt * 4);
            f32x4 r3 = *(const f32x4*)(Bf + (size_t)(k0 + fb_kt * 4 + 3) * N_GLOB + n0 + fb_nt * 4);
#pragma unroll
            for (int j = 0; j < 4; ++j) {
                u32x2 o;
                o.x = pack2_bf16(r0[j], r1[j]);
                o.y = pack2_bf16(r2[j], r3[j]);
                *(u32x2*)&Bs[fb_nt * 4 + j][fb_kt * 4] = o;
            }
        }

        __syncthreads();

        bf16x8 af[4], bfr[4];
#pragma unroll
        for (int i = 0; i < 4; ++i)
            af[i] = __builtin_bit_cast(bf16x8, *(const u32x4*)&As[wr * 64 + i * 16 + l16][quad * 8]);
#pragma unroll
        for (int j = 0; j < 4; ++j)
            bfr[j] = __builtin_bit_cast(bf16x8, *(const u32x4*)&Bs[wc * 64 + j * 16 + l16][quad * 8]);

#pragma unroll
        for (int i = 0; i < 4; ++i)
#pragma unroll
            for (int j = 0; j < 4; ++j)
                acc[i][j] = __builtin_amdgcn_mfma_f32_16x16x32_bf16(af[i], bfr[j], acc[i][j], 0, 0, 0);

        __syncthreads();
    }

    const float LN2 = 0.69314718055994530942f;
#pragma unroll
    for (int i = 0; i < 4; ++i) {
#pragma unroll
        for (int j = 0; j < 4; ++j) {
            const int col = n0 + wc * 64 + j * 16 + l16;
#pragma unroll
            for (int r = 0; r < 4; ++r) {
                const int row = m0 + wr * 64 + i * 16 + quad * 4 + r;
                float v = fmaxf(acc[i][j][r], 1.17549435e-38f);
                C[(size_t)row * N_GLOB + col] = __log2f(v) * LN2;
            }
        }
    }
}

extern "C" void kernel_launch(void* const* d_in, const int* in_sizes, int n_in,
                              void* d_out, int out_size, void* d_ws, size_t ws_size,
                              hipStream_t stream) {
    const float* A = (const float*)d_in[0];   // x: [16384,1024]
    const float* B = (const float*)d_in[1];   // matrix: [1024,1024]
    float* C = (float*)d_out;

    const size_t bt_bytes = (size_t)N_GLOB * K_GLOB;        // 1 MiB fp8
    const size_t ab_bytes = (size_t)M_GLOB * K_GLOB;        // 16 MiB fp8
    const int nA = (M_GLOB * K_GLOB) / (256 * 16);          // 4096 cvt blocks

    if (ws_size >= bt_bytes + ab_bytes) {
        u8* Bt = (u8*)d_ws;
        u8* Ab = (u8*)d_ws + bt_bytes;
        prep_fp8_kernel<<<nA + 1024, 256, 0, stream>>>(A, Ab, B, Bt, nA);
        gemm_mx_kernel<<<(M_GLOB / BM) * (N_GLOB / BN), 256, 0, stream>>>(Ab, Bt, C);
    } else {
        logmm_fused_kernel<<<dim3(N_GLOB / FBN, M_GLOB / FBM), 256, 0, stream>>>(A, B, C);
    }
}